// Round 1
// baseline (302.872 us; speedup 1.0000x reference)
//
#include <hip/hip_runtime.h>

#define DEV __device__ __forceinline__

using f32x4    = __attribute__((ext_vector_type(4))) float;
using bf16x8   = __attribute__((ext_vector_type(8))) short;     // 8 bf16 in 4 VGPRs (guide §3)
using float4_t = __attribute__((ext_vector_type(4))) float;
using ushort4_t = __attribute__((ext_vector_type(4))) unsigned short;
using ushort8_t = __attribute__((ext_vector_type(8))) unsigned short;

DEV unsigned short f2bf(float f) {                 // RNE float->bf16 (no NaNs in this workload)
    unsigned int u = __builtin_bit_cast(unsigned int, f);
    u = (u + 0x7fffu + ((u >> 16) & 1u)) >> 16;
    return (unsigned short)u;
}
DEV float bf2f(unsigned short h) {
    unsigned int u = ((unsigned int)h) << 16;
    return __builtin_bit_cast(float, u);
}

DEV void gload_lds16(const void* g, void* l) {     // async global->LDS, width 16 (guide §5)
    __builtin_amdgcn_global_load_lds((const __attribute__((address_space(1))) void*)g,
                                     (__attribute__((address_space(3))) void*)l, 16, 0, 0);
}

// Stage a TR x TC (bf16) tile from row-major src (leading dim ld elems) into linear LDS.
// LDS dest is wave-uniform base + lane*16 (HW constraint) -> linear row-major layout.
template<int TR, int TC, int NTH>
DEV void stage_tile(const unsigned short* __restrict__ src, long ld, long r0, long c0,
                    unsigned short* lds, int tid) {
    constexpr int LPR = (TC * 2) / 16;   // lanes per row (TC=64 -> 8)
    constexpr int RPI = 64 / LPR;        // rows per wave-issue (8)
    constexpr int NISSUE = TR / RPI;
    constexpr int NW = NTH / 64;
    const int wid = tid >> 6, lane = tid & 63;
#pragma unroll
    for (int ii = 0; ii < NISSUE / NW; ++ii) {
        const int i = ii * NW + wid;
        const long row = r0 + (long)i * RPI + (lane / LPR);
        const unsigned short* g = src + row * ld + c0 + (lane % LPR) * 8;
        gload_lds16(g, lds + i * 512);   // 512 elems = 1KB per wave-issue
    }
}

// ---------------- K0a: cast controller_output fp32 -> bf16 ----------------
__global__ void k0_cast_co(const float* __restrict__ in, unsigned short* __restrict__ out, long n4) {
    long i = (long)blockIdx.x * 256 + threadIdx.x;
    if (i >= n4) return;
    float4_t v = ((const float4_t*)in)[i];
    ushort4_t o;
#pragma unroll
    for (int j = 0; j < 4; ++j) o[j] = f2bf(v[j]);
    ((ushort4_t*)out)[i] = o;
}

// ---------------- K0b: WcatT[768][1024] = concat(Wk,We,Wa)^T in bf16 ----------------
__global__ void k0_prep_w(const float* __restrict__ Wk, const float* __restrict__ We,
                          const float* __restrict__ Wa, unsigned short* __restrict__ WcatT) {
    long idx = (long)blockIdx.x * 256 + threadIdx.x;   // 768*1024 total
    int j = (int)(idx >> 10), d = (int)(idx & 1023);
    const float* W = (j < 256) ? Wk : (j < 512) ? We : Wa;
    int m = j & 255;
    WcatT[idx] = f2bf(W[(long)d * 256 + m]);
}

// ---------------- K0c: mn = l2norm(memory) rows, bf16 ----------------
__global__ __launch_bounds__(256) void k0_mn(const float* __restrict__ memory,
                                             unsigned short* __restrict__ mn) {
    int row = blockIdx.x * 4 + (threadIdx.x >> 6);
    int lane = threadIdx.x & 63;
    float4_t v = ((const float4_t*)(memory + (long)row * 256))[lane];
    float ss = v[0]*v[0] + v[1]*v[1] + v[2]*v[2] + v[3]*v[3];
#pragma unroll
    for (int d = 1; d < 64; d <<= 1) ss += __shfl_xor(ss, d);
    float sc = rsqrtf(fmaxf(ss, 1e-12f));
    ushort4_t o;
#pragma unroll
    for (int j = 0; j < 4; ++j) o[j] = f2bf(v[j] * sc);
    ((ushort4_t*)(mn + (long)row * 256))[lane] = o;
}

__global__ void kz_zero(float* p, int n) {
    int i = blockIdx.x * 256 + threadIdx.x;
    if (i < n) p[i] = 0.f;
}

// ---------------- K1: logits[16384,768] = co_bf16 @ WcatT^T + bias ----------------
template<int BM, int BN, int BK>
__global__ __launch_bounds__(256, 2)
void k1_gemm_bias(const unsigned short* __restrict__ A, const unsigned short* __restrict__ BT,
                  float* __restrict__ C, int M, int N, int K,
                  const float* __restrict__ bk, const float* __restrict__ be,
                  const float* __restrict__ ba) {
    __shared__ __align__(16) unsigned short As[BM * BK];
    __shared__ __align__(16) unsigned short Bs[BN * BK];
    const int tid = threadIdx.x, lane = tid & 63, wid = tid >> 6;
    const long m0 = (long)blockIdx.x * BM, n0 = (long)blockIdx.y * BN;
    const int wr = (wid >> 1) * 64, wc = (wid & 1) * 64;
    f32x4 acc[4][4] = {};
    for (int kt = 0; kt < K; kt += BK) {
        stage_tile<BM, BK, 256>(A, K, m0, kt, As, tid);
        stage_tile<BN, BK, 256>(BT, K, n0, kt, Bs, tid);
        __syncthreads();
#pragma unroll
        for (int kk = 0; kk < BK; kk += 32) {
            const int klo = kk + (lane >> 4) * 8;
            bf16x8 af[4], bfr[4];
#pragma unroll
            for (int i = 0; i < 4; ++i) {
                af[i]  = *(const bf16x8*)&As[(wr + i * 16 + (lane & 15)) * BK + klo];
                bfr[i] = *(const bf16x8*)&Bs[(wc + i * 16 + (lane & 15)) * BK + klo];
            }
#pragma unroll
            for (int i = 0; i < 4; ++i)
#pragma unroll
                for (int j = 0; j < 4; ++j)
                    acc[i][j] = __builtin_amdgcn_mfma_f32_16x16x32_bf16(af[i], bfr[j], acc[i][j], 0, 0, 0);
        }
        __syncthreads();
    }
#pragma unroll
    for (int i = 0; i < 4; ++i) {
        const long rbase = m0 + wr + i * 16 + ((lane >> 4) * 4);
#pragma unroll
        for (int j = 0; j < 4; ++j) {
            const long col = n0 + wc + j * 16 + (lane & 15);
            float bias = (col < 256) ? bk[col] : (col < 512) ? be[col - 256] : ba[col - 512];
#pragma unroll
            for (int r = 0; r < 4; ++r)
                C[(rbase + r) * N + col] = acc[i][j][r] + bias;
        }
    }
}

// ---------------- K2: row epilogue: kn = e/||e|| (softmax+l2n fused), erase, add ----------------
__global__ __launch_bounds__(256) void k2_epilogue(const float* __restrict__ logits,
                                                   unsigned short* __restrict__ kn,
                                                   unsigned short* __restrict__ er,
                                                   unsigned short* __restrict__ ad) {
    const int row = blockIdx.x * 4 + (threadIdx.x >> 6);
    const int lane = threadIdx.x & 63;
    const float* L = logits + (long)row * 768;
    float4_t xk = ((const float4_t*)L)[lane];
    float4_t xe = ((const float4_t*)(L + 256))[lane];
    float4_t xa = ((const float4_t*)(L + 512))[lane];
    float mx = fmaxf(fmaxf(xk[0], xk[1]), fmaxf(xk[2], xk[3]));
#pragma unroll
    for (int d = 1; d < 64; d <<= 1) mx = fmaxf(mx, __shfl_xor(mx, d));
    float e[4]; float ss = 0.f;
#pragma unroll
    for (int j = 0; j < 4; ++j) { e[j] = __expf(xk[j] - mx); ss += e[j] * e[j]; }
#pragma unroll
    for (int d = 1; d < 64; d <<= 1) ss += __shfl_xor(ss, d);
    // l2n(softmax(x)) == e/||e||; sum(p^2) >= 1/256 so reference EPS never binds
    float sc = rsqrtf(ss);
    ushort4_t ok, oe, oa;
#pragma unroll
    for (int j = 0; j < 4; ++j) {
        ok[j] = f2bf(e[j] * sc);
        oe[j] = f2bf(1.f / (1.f + __expf(-xe[j])));
        oa[j] = f2bf(fmaxf(xa[j], 0.f));
    }
    ((ushort4_t*)(kn + (long)row * 256))[lane] = ok;
    ((ushort4_t*)(er + (long)row * 256))[lane] = oe;
    ((ushort4_t*)(ad + (long)row * 256))[lane] = oa;
}

// ---------------- K3: E^T[n, bt] = exp(-(kn . mn)), plus rowsums S[bt] ----------------
template<int BM, int BN, int BK>
__global__ __launch_bounds__(256, 2)
void k3_gemm_sims(const unsigned short* __restrict__ A, const unsigned short* __restrict__ BT,
                  unsigned short* __restrict__ ET, float* __restrict__ S,
                  int M, int N, int K) {
    __shared__ __align__(16) unsigned short As[BM * BK];
    __shared__ __align__(16) unsigned short Bs[BN * BK];
    __shared__ __align__(16) unsigned short Tr[BN][BM + 8];  // [col][row] stash for transposed store
    const int tid = threadIdx.x, lane = tid & 63, wid = tid >> 6;
    const long m0 = (long)blockIdx.x * BM, n0 = (long)blockIdx.y * BN;
    const int wr = (wid >> 1) * 64, wc = (wid & 1) * 64;
    f32x4 acc[4][4] = {};
    for (int kt = 0; kt < K; kt += BK) {
        stage_tile<BM, BK, 256>(A, K, m0, kt, As, tid);
        stage_tile<BN, BK, 256>(BT, K, n0, kt, Bs, tid);
        __syncthreads();
#pragma unroll
        for (int kk = 0; kk < BK; kk += 32) {
            const int klo = kk + (lane >> 4) * 8;
            bf16x8 af[4], bfr[4];
#pragma unroll
            for (int i = 0; i < 4; ++i) {
                af[i]  = *(const bf16x8*)&As[(wr + i * 16 + (lane & 15)) * BK + klo];
                bfr[i] = *(const bf16x8*)&Bs[(wc + i * 16 + (lane & 15)) * BK + klo];
            }
#pragma unroll
            for (int i = 0; i < 4; ++i)
#pragma unroll
                for (int j = 0; j < 4; ++j)
                    acc[i][j] = __builtin_amdgcn_mfma_f32_16x16x32_bf16(af[i], bfr[j], acc[i][j], 0, 0, 0);
        }
        __syncthreads();
    }
    // epilogue: e = exp(-sim) (|sim|<=1 -> no max needed); stash transposed; rowsum
    float rs[4][4];
#pragma unroll
    for (int i = 0; i < 4; ++i)
#pragma unroll
        for (int r = 0; r < 4; ++r) rs[i][r] = 0.f;
    const int c16 = lane & 15, rq = (lane >> 4) * 4;
#pragma unroll
    for (int i = 0; i < 4; ++i) {
#pragma unroll
        for (int j = 0; j < 4; ++j) {
            ushort4_t pk;
#pragma unroll
            for (int r = 0; r < 4; ++r) {
                float e = __expf(-acc[i][j][r]);
                rs[i][r] += e;
                pk[r] = f2bf(e);
            }
            *(ushort4_t*)&Tr[wc + j * 16 + c16][wr + i * 16 + rq] = pk;
        }
    }
#pragma unroll
    for (int d = 1; d < 16; d <<= 1)
#pragma unroll
        for (int i = 0; i < 4; ++i)
#pragma unroll
            for (int r = 0; r < 4; ++r) rs[i][r] += __shfl_xor(rs[i][r], d);
    if (c16 == 0) {
#pragma unroll
        for (int i = 0; i < 4; ++i)
#pragma unroll
            for (int r = 0; r < 4; ++r)
                atomicAdd(&S[m0 + wr + i * 16 + rq + r], rs[i][r]);
    }
    __syncthreads();
    // cooperative transposed write: ET[n0+c][m0 .. m0+BM)
    constexpr int CPR = BM / 8;  // 16-byte chunks per row
#pragma unroll
    for (int it = 0; it < (BN * CPR) / 256; ++it) {
        int flat = it * 256 + tid;
        int c = flat / CPR, ch = flat % CPR;
        *(ushort8_t*)&ET[(n0 + c) * (long)M + m0 + ch * 8] = *(const ushort8_t*)&Tr[c][ch * 8];
    }
}

// ---------------- K3c: e'[m,k] = src[k,m] * inv_bt / S[k], transposed ----------------
__global__ __launch_bounds__(256) void k3c_scale_transpose(
        const unsigned short* __restrict__ er, const unsigned short* __restrict__ ad,
        const float* __restrict__ S, unsigned short* __restrict__ ebT,
        unsigned short* __restrict__ abT, float inv_bt, int BTr) {
    const unsigned short* src = blockIdx.y ? ad : er;
    unsigned short* dst = blockIdx.y ? abT : ebT;
    __shared__ __align__(16) unsigned short Tl[64][256 + 8];
    const int tid = threadIdx.x;
    const long kbase = (long)blockIdx.x * 64;
#pragma unroll
    for (int it = 0; it < 8; ++it) {
        int flat = it * 2048 + tid * 8;
        int kl = flat >> 8, m = flat & 255;
        float scale = inv_bt / S[kbase + kl];
        ushort8_t v = *(const ushort8_t*)&src[(kbase + kl) * 256 + m];
        ushort8_t o;
#pragma unroll
        for (int j = 0; j < 8; ++j) o[j] = f2bf(bf2f(v[j]) * scale);
        *(ushort8_t*)&Tl[kl][m] = o;
    }
    __syncthreads();
#pragma unroll
    for (int it = 0; it < 8; ++it) {
        int flat = it * 2048 + tid * 8;
        int m = flat >> 6, kc = flat & 63;
        ushort8_t o;
#pragma unroll
        for (int j = 0; j < 8; ++j) o[j] = Tl[kc + j][m];
        *(ushort8_t*)&dst[(long)m * BTr + kbase + kc] = o;
    }
}

// ---------------- K4: split-K dual GEMM: partials of E^T @ e' and E^T @ a' ----------------
template<int BM, int BN, int BK>
__global__ __launch_bounds__(256, 2)
void k4_gemm_wewa(const unsigned short* __restrict__ A, const unsigned short* __restrict__ BTe,
                  const unsigned short* __restrict__ BTa, float* __restrict__ pWE,
                  float* __restrict__ pWA, int Mr, int Nc, long Ktot, int Kchunk) {
    __shared__ __align__(16) unsigned short As[BM * BK];
    __shared__ __align__(16) unsigned short Bes[BN * BK];
    __shared__ __align__(16) unsigned short Bas[BN * BK];
    const int tid = threadIdx.x, lane = tid & 63, wid = tid >> 6;
    const long n0 = (long)blockIdx.x * BM;
    const long m0 = (long)blockIdx.y * BN;
    const int sk = blockIdx.z;
    const long kbeg = (long)sk * Kchunk;
    const int wr = (wid >> 1) * 64, wc = (wid & 1) * 32;
    f32x4 ae[4][2] = {}, aa[4][2] = {};
    for (int kt = 0; kt < Kchunk; kt += BK) {
        stage_tile<BM, BK, 256>(A, Ktot, n0, kbeg + kt, As, tid);
        stage_tile<BN, BK, 256>(BTe, Ktot, m0, kbeg + kt, Bes, tid);
        stage_tile<BN, BK, 256>(BTa, Ktot, m0, kbeg + kt, Bas, tid);
        __syncthreads();
#pragma unroll
        for (int kk = 0; kk < BK; kk += 32) {
            const int klo = kk + (lane >> 4) * 8;
            bf16x8 af[4], bef[2], baf[2];
#pragma unroll
            for (int i = 0; i < 4; ++i)
                af[i] = *(const bf16x8*)&As[(wr + i * 16 + (lane & 15)) * BK + klo];
#pragma unroll
            for (int j = 0; j < 2; ++j) {
                bef[j] = *(const bf16x8*)&Bes[(wc + j * 16 + (lane & 15)) * BK + klo];
                baf[j] = *(const bf16x8*)&Bas[(wc + j * 16 + (lane & 15)) * BK + klo];
            }
#pragma unroll
            for (int i = 0; i < 4; ++i)
#pragma unroll
                for (int j = 0; j < 2; ++j) {
                    ae[i][j] = __builtin_amdgcn_mfma_f32_16x16x32_bf16(af[i], bef[j], ae[i][j], 0, 0, 0);
                    aa[i][j] = __builtin_amdgcn_mfma_f32_16x16x32_bf16(af[i], baf[j], aa[i][j], 0, 0, 0);
                }
        }
        __syncthreads();
    }
#pragma unroll
    for (int i = 0; i < 4; ++i) {
        const long row = n0 + wr + i * 16 + ((lane >> 4) * 4);
#pragma unroll
        for (int j = 0; j < 2; ++j) {
            const long col = m0 + wc + j * 16 + (lane & 15);
#pragma unroll
            for (int r = 0; r < 4; ++r) {
                const long idx = ((long)sk * Mr + row + r) * Nc + col;
                pWE[idx] = ae[i][j][r];
                pWA[idx] = aa[i][j][r];
            }
        }
    }
}

// ---------------- K5: out = memory*(1 - sum we) + sum wa ----------------
__global__ void k5_finalize(const float* __restrict__ mem, const float* __restrict__ pWE,
                            const float* __restrict__ pWA, float* __restrict__ out,
                            int total, int splits) {
    int i = blockIdx.x * 256 + threadIdx.x;
    if (i * 4 >= total) return;
    float4_t we = {0.f, 0.f, 0.f, 0.f}, wa = {0.f, 0.f, 0.f, 0.f};
    for (int s = 0; s < splits; ++s) {
        we += ((const float4_t*)pWE)[(long)s * (total / 4) + i];
        wa += ((const float4_t*)pWA)[(long)s * (total / 4) + i];
    }
    float4_t m = ((const float4_t*)mem)[i];
    float4_t o;
#pragma unroll
    for (int j = 0; j < 4; ++j) o[j] = m[j] * (1.f - we[j]) + wa[j];
    ((float4_t*)out)[i] = o;
}

extern "C" void kernel_launch(void* const* d_in, const int* in_sizes, int n_in,
                              void* d_out, int out_size, void* d_ws, size_t ws_size,
                              hipStream_t stream) {
    const float* memory = (const float*)d_in[0];
    const float* co     = (const float*)d_in[1];
    const float* Wk     = (const float*)d_in[2];
    const float* bk     = (const float*)d_in[3];
    const float* We     = (const float*)d_in[4];
    const float* be     = (const float*)d_in[5];
    const float* Wa     = (const float*)d_in[6];
    const float* ba     = (const float*)d_in[7];
    float* out = (float*)d_out;

    constexpr int BT = 16384, D = 1024, N = 2048, Mm = 256, NC = 768;
    constexpr int SPLITK = 4;

    // Workspace layout (bytes). ET (64Mi) aliases co_bf16+logits (dead after K2). ~139 MiB total.
    char* ws = (char*)d_ws;
    unsigned short* co_bf  = (unsigned short*)(ws + 0);           // 32 Mi  [K0a..K1]
    float*          logits = (float*)(ws + 33554432);             // 48 Mi  [K1..K2]
    unsigned short* ET     = (unsigned short*)(ws + 0);           // 64 Mi  [K3..K4]
    unsigned short* kn     = (unsigned short*)(ws + 83886080);    // 8 Mi
    unsigned short* er     = (unsigned short*)(ws + 92274688);    // 8 Mi
    unsigned short* ad     = (unsigned short*)(ws + 100663296);   // 8 Mi
    unsigned short* mn     = (unsigned short*)(ws + 109051904);   // 1 Mi
    unsigned short* WcatT  = (unsigned short*)(ws + 110100480);   // 1.5 Mi
    float*          Sbuf   = (float*)(ws + 111673344);            // 64 Ki
    unsigned short* ebT    = (unsigned short*)(ws + 111738880);   // 8 Mi
    unsigned short* abT    = (unsigned short*)(ws + 120127488);   // 8 Mi
    float*          pWE    = (float*)(ws + 128516096);            // 8 Mi (4 splits)
    float*          pWA    = (float*)(ws + 136904704);            // 8 Mi

    k0_cast_co<<<(BT * (long)D / 4) / 256, 256, 0, stream>>>(co, co_bf, BT * (long)D / 4);
    k0_prep_w<<<(NC * D) / 256, 256, 0, stream>>>(Wk, We, Wa, WcatT);
    k0_mn<<<N / 4, 256, 0, stream>>>(memory, mn);
    kz_zero<<<BT / 256, 256, 0, stream>>>(Sbuf, BT);

    k1_gemm_bias<128, 128, 64><<<dim3(BT / 128, NC / 128), 256, 0, stream>>>(
        co_bf, WcatT, logits, BT, NC, D, bk, be, ba);

    k2_epilogue<<<BT / 4, 256, 0, stream>>>(logits, kn, er, ad);

    k3_gemm_sims<128, 128, 64><<<dim3(BT / 128, N / 128), 256, 0, stream>>>(
        kn, mn, ET, Sbuf, BT, N, Mm);

    k3c_scale_transpose<<<dim3(BT / 64, 2), 256, 0, stream>>>(
        er, ad, Sbuf, ebT, abT, 1.f / (float)BT, BT);

    k4_gemm_wewa<128, 64, 64><<<dim3(N / 128, Mm / 64, SPLITK), 256, 0, stream>>>(
        ET, ebT, abT, pWE, pWA, N, Mm, (long)BT, BT / SPLITK);

    k5_finalize<<<(N * Mm / 4) / 256, 256, 0, stream>>>(memory, pWE, pWA, out, N * Mm, SPLITK);
}

// Round 2
// 275.902 us; speedup vs baseline: 1.0978x; 1.0978x over previous
//
#include <hip/hip_runtime.h>

#define DEV __device__ __forceinline__

using f32x4    = __attribute__((ext_vector_type(4))) float;
using bf16x8   = __attribute__((ext_vector_type(8))) short;     // 8 bf16 in 4 VGPRs (guide §3)
using float4_t = __attribute__((ext_vector_type(4))) float;
using ushort4_t = __attribute__((ext_vector_type(4))) unsigned short;
using ushort8_t = __attribute__((ext_vector_type(8))) unsigned short;

DEV unsigned short f2bf(float f) {                 // RNE float->bf16 (no NaNs in this workload)
    unsigned int u = __builtin_bit_cast(unsigned int, f);
    u = (u + 0x7fffu + ((u >> 16) & 1u)) >> 16;
    return (unsigned short)u;
}
DEV float bf2f(unsigned short h) {
    unsigned int u = ((unsigned int)h) << 16;
    return __builtin_bit_cast(float, u);
}

DEV void gload_lds16(const void* g, void* l) {     // async global->LDS, width 16 (guide §5)
    __builtin_amdgcn_global_load_lds((const __attribute__((address_space(1))) void*)g,
                                     (__attribute__((address_space(3))) void*)l, 16, 0, 0);
}

// Stage a TR x TC (bf16) tile from row-major src (leading dim ld elems) into linear LDS.
// LDS dest is wave-uniform base + lane*16 (HW constraint) -> linear row-major layout.
template<int TR, int TC, int NTH>
DEV void stage_tile(const unsigned short* __restrict__ src, long ld, long r0, long c0,
                    unsigned short* lds, int tid) {
    constexpr int LPR = (TC * 2) / 16;   // lanes per row (TC=64 -> 8)
    constexpr int RPI = 64 / LPR;        // rows per wave-issue (8)
    constexpr int NISSUE = TR / RPI;
    constexpr int NW = NTH / 64;
    const int wid = tid >> 6, lane = tid & 63;
#pragma unroll
    for (int ii = 0; ii < NISSUE / NW; ++ii) {
        const int i = ii * NW + wid;
        const long row = r0 + (long)i * RPI + (lane / LPR);
        const unsigned short* g = src + row * ld + c0 + (lane % LPR) * 8;
        gload_lds16(g, lds + i * 512);   // 512 elems = 1KB per wave-issue
    }
}

// ---------------- K0a: cast controller_output fp32 -> bf16 ----------------
__global__ void k0_cast_co(const float* __restrict__ in, unsigned short* __restrict__ out, long n4) {
    long i = (long)blockIdx.x * 256 + threadIdx.x;
    if (i >= n4) return;
    float4_t v = ((const float4_t*)in)[i];
    ushort4_t o;
#pragma unroll
    for (int j = 0; j < 4; ++j) o[j] = f2bf(v[j]);
    ((ushort4_t*)out)[i] = o;
}

// ---------------- K0b: WcatT[768][1024] = concat(Wk,We,Wa)^T in bf16 ----------------
__global__ void k0_prep_w(const float* __restrict__ Wk, const float* __restrict__ We,
                          const float* __restrict__ Wa, unsigned short* __restrict__ WcatT) {
    long idx = (long)blockIdx.x * 256 + threadIdx.x;   // 768*1024 total
    int j = (int)(idx >> 10), d = (int)(idx & 1023);
    const float* W = (j < 256) ? Wk : (j < 512) ? We : Wa;
    int m = j & 255;
    WcatT[idx] = f2bf(W[(long)d * 256 + m]);
}

// ---------------- K0c: mn = l2norm(memory) rows bf16; also zero S (fused) ----------------
__global__ __launch_bounds__(256) void k0_mn(const float* __restrict__ memory,
                                             unsigned short* __restrict__ mn,
                                             float* __restrict__ S, int BT) {
    int gid = blockIdx.x * 256 + threadIdx.x;
    if (gid < BT) S[gid] = 0.f;
    int row = blockIdx.x * 4 + (threadIdx.x >> 6);
    int lane = threadIdx.x & 63;
    float4_t v = ((const float4_t*)(memory + (long)row * 256))[lane];
    float ss = v[0]*v[0] + v[1]*v[1] + v[2]*v[2] + v[3]*v[3];
#pragma unroll
    for (int d = 1; d < 64; d <<= 1) ss += __shfl_xor(ss, d);
    float sc = rsqrtf(fmaxf(ss, 1e-12f));
    ushort4_t o;
#pragma unroll
    for (int j = 0; j < 4; ++j) o[j] = f2bf(v[j] * sc);
    ((ushort4_t*)(mn + (long)row * 256))[lane] = o;
}

// ---------------- K1: logits[16384,768] = co_bf16 @ WcatT^T + bias ----------------
template<int BM, int BN, int BK>
__global__ __launch_bounds__(256, 3)
void k1_gemm_bias(const unsigned short* __restrict__ A, const unsigned short* __restrict__ BT,
                  float* __restrict__ C, int M, int N, int K,
                  const float* __restrict__ bk, const float* __restrict__ be,
                  const float* __restrict__ ba) {
    __shared__ __align__(16) unsigned short As[BM * BK];
    __shared__ __align__(16) unsigned short Bs[BN * BK];
    const int tid = threadIdx.x, lane = tid & 63, wid = tid >> 6;
    const long m0 = (long)blockIdx.x * BM, n0 = (long)blockIdx.y * BN;
    const int wr = (wid >> 1) * 64, wc = (wid & 1) * 64;
    f32x4 acc[4][4] = {};
    for (int kt = 0; kt < K; kt += BK) {
        stage_tile<BM, BK, 256>(A, K, m0, kt, As, tid);
        stage_tile<BN, BK, 256>(BT, K, n0, kt, Bs, tid);
        __syncthreads();
#pragma unroll
        for (int kk = 0; kk < BK; kk += 32) {
            const int klo = kk + (lane >> 4) * 8;
            bf16x8 af[4], bfr[4];
#pragma unroll
            for (int i = 0; i < 4; ++i) {
                af[i]  = *(const bf16x8*)&As[(wr + i * 16 + (lane & 15)) * BK + klo];
                bfr[i] = *(const bf16x8*)&Bs[(wc + i * 16 + (lane & 15)) * BK + klo];
            }
#pragma unroll
            for (int i = 0; i < 4; ++i)
#pragma unroll
                for (int j = 0; j < 4; ++j)
                    acc[i][j] = __builtin_amdgcn_mfma_f32_16x16x32_bf16(af[i], bfr[j], acc[i][j], 0, 0, 0);
        }
        __syncthreads();
    }
#pragma unroll
    for (int i = 0; i < 4; ++i) {
        const long rbase = m0 + wr + i * 16 + ((lane >> 4) * 4);
#pragma unroll
        for (int j = 0; j < 4; ++j) {
            const long col = n0 + wc + j * 16 + (lane & 15);
            float bias = (col < 256) ? bk[col] : (col < 512) ? be[col - 256] : ba[col - 512];
#pragma unroll
            for (int r = 0; r < 4; ++r)
                C[(rbase + r) * N + col] = acc[i][j][r] + bias;
        }
    }
}

// ---------------- K2: row epilogue: kn = e/||e|| (softmax+l2n fused), erase, add ----------------
__global__ __launch_bounds__(256) void k2_epilogue(const float* __restrict__ logits,
                                                   unsigned short* __restrict__ kn,
                                                   unsigned short* __restrict__ er,
                                                   unsigned short* __restrict__ ad) {
    const int row = blockIdx.x * 4 + (threadIdx.x >> 6);
    const int lane = threadIdx.x & 63;
    const float* L = logits + (long)row * 768;
    float4_t xk = ((const float4_t*)L)[lane];
    float4_t xe = ((const float4_t*)(L + 256))[lane];
    float4_t xa = ((const float4_t*)(L + 512))[lane];
    float mx = fmaxf(fmaxf(xk[0], xk[1]), fmaxf(xk[2], xk[3]));
#pragma unroll
    for (int d = 1; d < 64; d <<= 1) mx = fmaxf(mx, __shfl_xor(mx, d));
    float e[4]; float ss = 0.f;
#pragma unroll
    for (int j = 0; j < 4; ++j) { e[j] = __expf(xk[j] - mx); ss += e[j] * e[j]; }
#pragma unroll
    for (int d = 1; d < 64; d <<= 1) ss += __shfl_xor(ss, d);
    // l2n(softmax(x)) == e/||e||; sum(p^2) >= 1/256 so reference EPS never binds
    float sc = rsqrtf(ss);
    ushort4_t ok, oe, oa;
#pragma unroll
    for (int j = 0; j < 4; ++j) {
        ok[j] = f2bf(e[j] * sc);
        oe[j] = f2bf(1.f / (1.f + __expf(-xe[j])));
        oa[j] = f2bf(fmaxf(xa[j], 0.f));
    }
    ((ushort4_t*)(kn + (long)row * 256))[lane] = ok;
    ((ushort4_t*)(er + (long)row * 256))[lane] = oe;
    ((ushort4_t*)(ad + (long)row * 256))[lane] = oa;
}

// ---------------- K3: E^T[n, bt] = exp(-(kn . mn)), plus rowsums S[bt] ----------------
// LDS union: Tr (post-loop transpose stash) overlays As/Bs -> 34.8 KiB total, 3 blocks/CU.
template<int BM, int BN, int BK>
__global__ __launch_bounds__(256, 3)
void k3_gemm_sims(const unsigned short* __restrict__ A, const unsigned short* __restrict__ BT,
                  unsigned short* __restrict__ ET, float* __restrict__ S,
                  int M, int N, int K) {
    __shared__ __align__(16) unsigned short smem[BN * (BM + 8)];   // >= As(BM*BK)+Bs(BN*BK)
    unsigned short* As = smem;
    unsigned short* Bs = smem + BM * BK;
    const int tid = threadIdx.x, lane = tid & 63, wid = tid >> 6;
    const long m0 = (long)blockIdx.x * BM, n0 = (long)blockIdx.y * BN;
    const int wr = (wid >> 1) * 64, wc = (wid & 1) * 64;
    f32x4 acc[4][4] = {};
    for (int kt = 0; kt < K; kt += BK) {
        stage_tile<BM, BK, 256>(A, K, m0, kt, As, tid);
        stage_tile<BN, BK, 256>(BT, K, n0, kt, Bs, tid);
        __syncthreads();
#pragma unroll
        for (int kk = 0; kk < BK; kk += 32) {
            const int klo = kk + (lane >> 4) * 8;
            bf16x8 af[4], bfr[4];
#pragma unroll
            for (int i = 0; i < 4; ++i) {
                af[i]  = *(const bf16x8*)&As[(wr + i * 16 + (lane & 15)) * BK + klo];
                bfr[i] = *(const bf16x8*)&Bs[(wc + i * 16 + (lane & 15)) * BK + klo];
            }
#pragma unroll
            for (int i = 0; i < 4; ++i)
#pragma unroll
                for (int j = 0; j < 4; ++j)
                    acc[i][j] = __builtin_amdgcn_mfma_f32_16x16x32_bf16(af[i], bfr[j], acc[i][j], 0, 0, 0);
        }
        __syncthreads();   // also fences last fragment reads before Tr overlays As/Bs
    }
    // epilogue: e = exp(-sim) (|sim|<=1 -> no max needed); stash transposed; rowsum
    float rs[4][4];
#pragma unroll
    for (int i = 0; i < 4; ++i)
#pragma unroll
        for (int r = 0; r < 4; ++r) rs[i][r] = 0.f;
    const int c16 = lane & 15, rq = (lane >> 4) * 4;
#pragma unroll
    for (int i = 0; i < 4; ++i) {
#pragma unroll
        for (int j = 0; j < 4; ++j) {
            ushort4_t pk;
#pragma unroll
            for (int r = 0; r < 4; ++r) {
                float e = __expf(-acc[i][j][r]);
                rs[i][r] += e;
                pk[r] = f2bf(e);
            }
            *(ushort4_t*)&smem[(wc + j * 16 + c16) * (BM + 8) + wr + i * 16 + rq] = pk;
        }
    }
#pragma unroll
    for (int d = 1; d < 16; d <<= 1)
#pragma unroll
        for (int i = 0; i < 4; ++i)
#pragma unroll
            for (int r = 0; r < 4; ++r) rs[i][r] += __shfl_xor(rs[i][r], d);
    if (c16 == 0) {
#pragma unroll
        for (int i = 0; i < 4; ++i)
#pragma unroll
            for (int r = 0; r < 4; ++r)
                atomicAdd(&S[m0 + wr + i * 16 + rq + r], rs[i][r]);
    }
    __syncthreads();
    // cooperative transposed write: ET[n0+c][m0 .. m0+BM)
    constexpr int CPR = BM / 8;  // 16-byte chunks per row
#pragma unroll
    for (int it = 0; it < (BN * CPR) / 256; ++it) {
        int flat = it * 256 + tid;
        int c = flat / CPR, ch = flat % CPR;
        *(ushort8_t*)&ET[(n0 + c) * (long)M + m0 + ch * 8] =
            *(const ushort8_t*)&smem[c * (BM + 8) + ch * 8];
    }
}

// ---------------- K3c: cat[m,k] = src[k,m] * inv_bt / S[k], transposed ----------------
__global__ __launch_bounds__(256) void k3c_scale_transpose(
        const unsigned short* __restrict__ er, const unsigned short* __restrict__ ad,
        const float* __restrict__ S, unsigned short* __restrict__ cat,
        float inv_bt, int BTr) {
    const unsigned short* src = blockIdx.y ? ad : er;
    unsigned short* dst = cat + (blockIdx.y ? (long)256 * BTr : 0);
    __shared__ __align__(16) unsigned short Tl[64][256 + 8];
    const int tid = threadIdx.x;
    const long kbase = (long)blockIdx.x * 64;
#pragma unroll
    for (int it = 0; it < 8; ++it) {
        int flat = it * 2048 + tid * 8;
        int kl = flat >> 8, m = flat & 255;
        float scale = inv_bt / S[kbase + kl];
        ushort8_t v = *(const ushort8_t*)&src[(kbase + kl) * 256 + m];
        ushort8_t o;
#pragma unroll
        for (int j = 0; j < 8; ++j) o[j] = f2bf(bf2f(v[j]) * scale);
        *(ushort8_t*)&Tl[kl][m] = o;
    }
    __syncthreads();
#pragma unroll
    for (int it = 0; it < 8; ++it) {
        int flat = it * 2048 + tid * 8;
        int m = flat >> 6, kc = flat & 63;
        ushort8_t o;
#pragma unroll
        for (int j = 0; j < 8; ++j) o[j] = Tl[kc + j][m];
        *(ushort8_t*)&dst[(long)m * BTr + kbase + kc] = o;
    }
}

// ---------------- K4: split-K GEMM: partial[2048,512] = ET @ cat^T (512 thr, 8 waves) ----------------
template<int BM, int BN, int BK>
__global__ __launch_bounds__(512, 2)
void k4_gemm_cat(const unsigned short* __restrict__ A, const unsigned short* __restrict__ Bc,
                 float* __restrict__ pWE, float* __restrict__ pWA, long Ktot, int Kchunk) {
    __shared__ __align__(16) unsigned short As[BM * BK];
    __shared__ __align__(16) unsigned short Bs[BN * BK];
    const int tid = threadIdx.x, lane = tid & 63, wid = tid >> 6;   // wid 0..7
    const long n0 = (long)blockIdx.x * BM;        // output row (n of 2048)
    const long mc0 = (long)blockIdx.y * BN;       // concat col (of 512)
    const int sk = blockIdx.z;
    const long kbeg = (long)sk * Kchunk;
    const int wr = (wid >> 2) * 64, wc = (wid & 3) * 32;   // 2x4 waves, 64x32 tiles
    f32x4 acc[4][2] = {};
    for (int kt = 0; kt < Kchunk; kt += BK) {
        stage_tile<BM, BK, 512>(A, Ktot, n0, kbeg + kt, As, tid);
        stage_tile<BN, BK, 512>(Bc, Ktot, mc0, kbeg + kt, Bs, tid);
        __syncthreads();
#pragma unroll
        for (int kk = 0; kk < BK; kk += 32) {
            const int klo = kk + (lane >> 4) * 8;
            bf16x8 af[4], bfr[2];
#pragma unroll
            for (int i = 0; i < 4; ++i)
                af[i] = *(const bf16x8*)&As[(wr + i * 16 + (lane & 15)) * BK + klo];
#pragma unroll
            for (int j = 0; j < 2; ++j)
                bfr[j] = *(const bf16x8*)&Bs[(wc + j * 16 + (lane & 15)) * BK + klo];
#pragma unroll
            for (int i = 0; i < 4; ++i)
#pragma unroll
                for (int j = 0; j < 2; ++j)
                    acc[i][j] = __builtin_amdgcn_mfma_f32_16x16x32_bf16(af[i], bfr[j], acc[i][j], 0, 0, 0);
        }
        __syncthreads();
    }
    float* dst = (blockIdx.y < 2) ? pWE : pWA;
    const long cb = (blockIdx.y & 1) * BN;
#pragma unroll
    for (int i = 0; i < 4; ++i) {
        const long row = n0 + wr + i * 16 + ((lane >> 4) * 4);
#pragma unroll
        for (int j = 0; j < 2; ++j) {
            const long col = cb + wc + j * 16 + (lane & 15);
#pragma unroll
            for (int r = 0; r < 4; ++r)
                dst[((long)sk * 2048 + row + r) * 256 + col] = acc[i][j][r];
        }
    }
}

// ---------------- K5: out = memory*(1 - sum we) + sum wa ----------------
__global__ void k5_finalize(const float* __restrict__ mem, const float* __restrict__ pWE,
                            const float* __restrict__ pWA, float* __restrict__ out,
                            int total, int splits) {
    int i = blockIdx.x * 256 + threadIdx.x;
    if (i * 4 >= total) return;
    float4_t we = {0.f, 0.f, 0.f, 0.f}, wa = {0.f, 0.f, 0.f, 0.f};
    for (int s = 0; s < splits; ++s) {
        we += ((const float4_t*)pWE)[(long)s * (total / 4) + i];
        wa += ((const float4_t*)pWA)[(long)s * (total / 4) + i];
    }
    float4_t m = ((const float4_t*)mem)[i];
    float4_t o;
#pragma unroll
    for (int j = 0; j < 4; ++j) o[j] = m[j] * (1.f - we[j]) + wa[j];
    ((float4_t*)out)[i] = o;
}

extern "C" void kernel_launch(void* const* d_in, const int* in_sizes, int n_in,
                              void* d_out, int out_size, void* d_ws, size_t ws_size,
                              hipStream_t stream) {
    const float* memory = (const float*)d_in[0];
    const float* co     = (const float*)d_in[1];
    const float* Wk     = (const float*)d_in[2];
    const float* bk     = (const float*)d_in[3];
    const float* We     = (const float*)d_in[4];
    const float* be     = (const float*)d_in[5];
    const float* Wa     = (const float*)d_in[6];
    const float* ba     = (const float*)d_in[7];
    float* out = (float*)d_out;

    constexpr int BT = 16384, D = 1024, N = 2048, Mm = 256, NC = 768;
    constexpr int SPLITK = 8;

    // Workspace layout (bytes), lifetime-aliased; peak 122.6 MiB:
    //  [0,32Mi)   co_bf   (K0a..K1)      } overlaid by ET [0,64Mi) (K3..K4)
    //  [32,80Mi)  logits  (K1..K2)       } pWA [64,80Mi) (K4..K5) over dead logits tail
    //  [80,88Mi)  kn      (K2..K3)       } pWE [80,96Mi) (K4..K5) over dead kn+er
    //  [88,96Mi)  er      (K2..K3c)
    //  [96,104Mi) ad      (K2..K3c)
    //  [104Mi..]  mn(1Mi) WcatT(1.5Mi) S(64Ki)
    //  [106.56Mi..122.56Mi) cat[512,16384] (K3c..K4)
    char* ws = (char*)d_ws;
    unsigned short* co_bf  = (unsigned short*)(ws + 0);
    float*          logits = (float*)(ws + 33554432);
    unsigned short* ET     = (unsigned short*)(ws + 0);
    float*          pWA    = (float*)(ws + 67108864);
    unsigned short* kn     = (unsigned short*)(ws + 83886080);
    float*          pWE    = (float*)(ws + 83886080);
    unsigned short* er     = (unsigned short*)(ws + 92274688);
    unsigned short* ad     = (unsigned short*)(ws + 100663296);
    unsigned short* mn     = (unsigned short*)(ws + 109051904);
    unsigned short* WcatT  = (unsigned short*)(ws + 110100480);
    float*          Sbuf   = (float*)(ws + 111673344);
    unsigned short* cat    = (unsigned short*)(ws + 111738880);

    k0_cast_co<<<(BT * (long)D / 4) / 256, 256, 0, stream>>>(co, co_bf, BT * (long)D / 4);
    k0_prep_w<<<(NC * D) / 256, 256, 0, stream>>>(Wk, We, Wa, WcatT);
    k0_mn<<<N / 4, 256, 0, stream>>>(memory, mn, Sbuf, BT);

    k1_gemm_bias<128, 128, 64><<<dim3(BT / 128, NC / 128), 256, 0, stream>>>(
        co_bf, WcatT, logits, BT, NC, D, bk, be, ba);

    k2_epilogue<<<BT / 4, 256, 0, stream>>>(logits, kn, er, ad);

    k3_gemm_sims<128, 128, 64><<<dim3(BT / 128, N / 128), 256, 0, stream>>>(
        kn, mn, ET, Sbuf, BT, N, Mm);

    k3c_scale_transpose<<<dim3(BT / 64, 2), 256, 0, stream>>>(
        er, ad, Sbuf, cat, 1.f / (float)BT, BT);

    k4_gemm_cat<128, 128, 64><<<dim3(N / 128, 512 / 128, SPLITK), 512, 0, stream>>>(
        ET, cat, pWE, pWA, (long)BT, BT / SPLITK);

    k5_finalize<<<(N * Mm / 4) / 256, 256, 0, stream>>>(memory, pWE, pWA, out, N * Mm, SPLITK);
}

// Round 4
// 239.764 us; speedup vs baseline: 1.2632x; 1.1507x over previous
//
#include <hip/hip_runtime.h>

#define DEV __device__ __forceinline__

using f32x4    = __attribute__((ext_vector_type(4))) float;
using bf16x8   = __attribute__((ext_vector_type(8))) short;     // 8 bf16 in 4 VGPRs (guide §3)
using float4_t = __attribute__((ext_vector_type(4))) float;
using ushort4_t = __attribute__((ext_vector_type(4))) unsigned short;
using ushort8_t = __attribute__((ext_vector_type(8))) unsigned short;

DEV unsigned short f2bf(float f) {                 // RNE float->bf16 (no NaNs in this workload)
    unsigned int u = __builtin_bit_cast(unsigned int, f);
    u = (u + 0x7fffu + ((u >> 16) & 1u)) >> 16;
    return (unsigned short)u;
}
DEV float bf2f(unsigned short h) {
    unsigned int u = ((unsigned int)h) << 16;
    return __builtin_bit_cast(float, u);
}

DEV void gload_lds16(const void* g, void* l) {     // async global->LDS, width 16 (guide §5)
    __builtin_amdgcn_global_load_lds((const __attribute__((address_space(1))) void*)g,
                                     (__attribute__((address_space(3))) void*)l, 16, 0, 0);
}

// Stage a TR x 64 (bf16) tile from row-major src into LDS with T2 XOR-swizzle.
// LDS dest is linear (wave-uniform base + lane*16, HW constraint); the SOURCE chunk is
// pre-swizzled: LDS slot (row, chunk) holds global chunk (chunk ^ (row&7)) -- rule #21.
// Readers must XOR their elem offset with ((row&7)*8).
template<int TR, int TC, int NTH>
DEV void stage_tile(const unsigned short* __restrict__ src, long ld, long r0, long c0,
                    unsigned short* lds, int tid) {
    constexpr int LPR = (TC * 2) / 16;   // lanes per row (TC=64 -> 8)
    constexpr int RPI = 64 / LPR;        // rows per wave-issue (8)
    constexpr int NISSUE = TR / RPI;
    constexpr int NW = NTH / 64;
    const int wid = tid >> 6, lane = tid & 63;
    const int lr = lane / LPR;                 // row-in-group = (row & 7)
    const int lc = (lane % LPR) ^ lr;          // swizzled source chunk
#pragma unroll
    for (int ii = 0; ii < NISSUE / NW; ++ii) {
        const int i = ii * NW + wid;
        const long row = r0 + (long)i * RPI + lr;
        const unsigned short* g = src + row * ld + c0 + lc * 8;
        gload_lds16(g, lds + i * 512);   // 512 elems = 1KB per wave-issue
    }
}

// ---------------- K0a: cast controller_output fp32 -> bf16 ----------------
__global__ void k0_cast_co(const float* __restrict__ in, unsigned short* __restrict__ out, long n4) {
    long i = (long)blockIdx.x * 256 + threadIdx.x;
    if (i >= n4) return;
    float4_t v = ((const float4_t*)in)[i];
    ushort4_t o;
#pragma unroll
    for (int j = 0; j < 4; ++j) o[j] = f2bf(v[j]);
    ((ushort4_t*)out)[i] = o;
}

// ---------------- K0b: WcatT[768][1024] = concat(Wk,We,Wa)^T in bf16 ----------------
__global__ void k0_prep_w(const float* __restrict__ Wk, const float* __restrict__ We,
                          const float* __restrict__ Wa, unsigned short* __restrict__ WcatT) {
    long idx = (long)blockIdx.x * 256 + threadIdx.x;   // 768*1024 total
    int j = (int)(idx >> 10), d = (int)(idx & 1023);
    const float* W = (j < 256) ? Wk : (j < 512) ? We : Wa;
    int m = j & 255;
    WcatT[idx] = f2bf(W[(long)d * 256 + m]);
}

// ---------------- K0c: mn = l2norm(memory) rows bf16; also zero S (fused) ----------------
__global__ __launch_bounds__(256) void k0_mn(const float* __restrict__ memory,
                                             unsigned short* __restrict__ mn,
                                             float* __restrict__ S, int BT) {
    int gid = blockIdx.x * 256 + threadIdx.x;
    if (gid < BT) S[gid] = 0.f;
    int row = blockIdx.x * 4 + (threadIdx.x >> 6);
    int lane = threadIdx.x & 63;
    float4_t v = ((const float4_t*)(memory + (long)row * 256))[lane];
    float ss = v[0]*v[0] + v[1]*v[1] + v[2]*v[2] + v[3]*v[3];
#pragma unroll
    for (int d = 1; d < 64; d <<= 1) ss += __shfl_xor(ss, d);
    float sc = rsqrtf(fmaxf(ss, 1e-12f));
    ushort4_t o;
#pragma unroll
    for (int j = 0; j < 4; ++j) o[j] = f2bf(v[j] * sc);
    ((ushort4_t*)(mn + (long)row * 256))[lane] = o;
}

// ---------------- K1-fused: per y-tile (256 cols = one weight group) GEMM + epilogue ----
// y=0: kn = e/||e|| (softmax+l2n fused; no max-sub needed, logits ~N(0,1))
// y=1: er = sigmoid;  y=2: ad = relu.  Kills the 48MiB logits roundtrip + K2 launch.
template<int BM, int BN, int BK>   // 128, 256, 64
__global__ __launch_bounds__(512, 4)
void k1_fused(const unsigned short* __restrict__ A, const unsigned short* __restrict__ BT,
              const float* __restrict__ bk, const float* __restrict__ be,
              const float* __restrict__ ba, unsigned short* __restrict__ kn,
              unsigned short* __restrict__ er, unsigned short* __restrict__ ad, int K) {
    __shared__ __align__(16) unsigned short As[BM * BK];
    __shared__ __align__(16) unsigned short Bs[BN * BK];
    const int tid = threadIdx.x, lane = tid & 63, wid = tid >> 6;
    const long m0 = (long)blockIdx.x * BM;
    const int y = blockIdx.y;
    const int wrg = wid >> 2, wcg = wid & 3;
    const int wr = wrg * 64, wc = wcg * 64;
    const int c16 = lane & 15, rq = (lane >> 4) * 4, swz = (lane & 7) * 8;
    f32x4 acc[4][4] = {};
    for (int kt = 0; kt < K; kt += BK) {
        stage_tile<BM, BK, 512>(A, K, m0, kt, As, tid);
        stage_tile<BN, BK, 512>(BT, K, (long)y * BN, kt, Bs, tid);
        __syncthreads();
#pragma unroll
        for (int kk = 0; kk < BK; kk += 32) {
            const int klo = kk + (lane >> 4) * 8;
            bf16x8 af[4], bfr[4];
#pragma unroll
            for (int i = 0; i < 4; ++i) {
                af[i]  = *(const bf16x8*)&As[((wr + i * 16 + c16) * BK + klo) ^ swz];
                bfr[i] = *(const bf16x8*)&Bs[((wc + i * 16 + c16) * BK + klo) ^ swz];
            }
#pragma unroll
            for (int i = 0; i < 4; ++i)
#pragma unroll
                for (int j = 0; j < 4; ++j)
                    acc[i][j] = __builtin_amdgcn_mfma_f32_16x16x32_bf16(af[i], bfr[j], acc[i][j], 0, 0, 0);
        }
        __syncthreads();
    }
    const float* bias = (y == 0) ? bk : (y == 1) ? be : ba;
    float bj[4];
#pragma unroll
    for (int j = 0; j < 4; ++j) bj[j] = bias[wc + j * 16 + c16];

    if (y == 0) {
        // softmax + l2n: kn = e / sqrt(sum e^2), e = exp(logit) (bounded, f32-safe)
        float* redsm = (float*)As;   // [2 wrg][4 wcg][64 rows] overlay (post-loop, fenced)
#pragma unroll
        for (int i = 0; i < 4; ++i) {
            float p[4] = {0.f, 0.f, 0.f, 0.f};
#pragma unroll
            for (int j = 0; j < 4; ++j)
#pragma unroll
                for (int r = 0; r < 4; ++r) {
                    float e = __expf(acc[i][j][r] + bj[j]);
                    acc[i][j][r] = e;
                    p[r] += e * e;
                }
#pragma unroll
            for (int d = 1; d < 16; d <<= 1)
#pragma unroll
                for (int r = 0; r < 4; ++r) p[r] += __shfl_xor(p[r], d);
            if (c16 == 0) {
#pragma unroll
                for (int r = 0; r < 4; ++r)
                    redsm[(wrg * 4 + wcg) * 64 + i * 16 + rq + r] = p[r];
            }
        }
        __syncthreads();
#pragma unroll
        for (int i = 0; i < 4; ++i)
#pragma unroll
            for (int r = 0; r < 4; ++r) {
                const int row64 = i * 16 + rq + r;
                float tot = redsm[(wrg * 4 + 0) * 64 + row64] + redsm[(wrg * 4 + 1) * 64 + row64]
                          + redsm[(wrg * 4 + 2) * 64 + row64] + redsm[(wrg * 4 + 3) * 64 + row64];
                float sc = rsqrtf(tot);
                const long row = m0 + wr + row64;
#pragma unroll
                for (int j = 0; j < 4; ++j)
                    kn[row * 256 + wc + j * 16 + c16] = f2bf(acc[i][j][r] * sc);
            }
    } else {
        unsigned short* dst = (y == 1) ? er : ad;
#pragma unroll
        for (int i = 0; i < 4; ++i)
#pragma unroll
            for (int r = 0; r < 4; ++r) {
                const long row = m0 + wr + i * 16 + rq + r;
#pragma unroll
                for (int j = 0; j < 4; ++j) {
                    float v = acc[i][j][r] + bj[j];
                    float o = (y == 1) ? 1.f / (1.f + __expf(-v)) : fmaxf(v, 0.f);
                    dst[row * 256 + wc + j * 16 + c16] = f2bf(o);
                }
            }
    }
}

// ---------------- K3: E^T[n, bt] = exp(-(kn . mn)), plus rowsums S[bt] ----------------
template<int BM, int BN, int BK>
__global__ __launch_bounds__(256, 4)
void k3_gemm_sims(const unsigned short* __restrict__ A, const unsigned short* __restrict__ BT,
                  unsigned short* __restrict__ ET, float* __restrict__ S,
                  int M, int N, int K) {
    __shared__ __align__(16) unsigned short smem[BN * (BM + 8)];   // >= As(BM*BK)+Bs(BN*BK)
    unsigned short* As = smem;
    unsigned short* Bs = smem + BM * BK;
    const int tid = threadIdx.x, lane = tid & 63, wid = tid >> 6;
    const long m0 = (long)blockIdx.x * BM, n0 = (long)blockIdx.y * BN;
    const int wr = (wid >> 1) * 64, wc = (wid & 1) * 64;
    const int c16 = lane & 15, rq = (lane >> 4) * 4, swz = (lane & 7) * 8;
    f32x4 acc[4][4] = {};
    for (int kt = 0; kt < K; kt += BK) {
        stage_tile<BM, BK, 256>(A, K, m0, kt, As, tid);
        stage_tile<BN, BK, 256>(BT, K, n0, kt, Bs, tid);
        __syncthreads();
#pragma unroll
        for (int kk = 0; kk < BK; kk += 32) {
            const int klo = kk + (lane >> 4) * 8;
            bf16x8 af[4], bfr[4];
#pragma unroll
            for (int i = 0; i < 4; ++i) {
                af[i]  = *(const bf16x8*)&As[((wr + i * 16 + c16) * BK + klo) ^ swz];
                bfr[i] = *(const bf16x8*)&Bs[((wc + i * 16 + c16) * BK + klo) ^ swz];
            }
#pragma unroll
            for (int i = 0; i < 4; ++i)
#pragma unroll
                for (int j = 0; j < 4; ++j)
                    acc[i][j] = __builtin_amdgcn_mfma_f32_16x16x32_bf16(af[i], bfr[j], acc[i][j], 0, 0, 0);
        }
        __syncthreads();   // also fences last fragment reads before Tr overlays As/Bs
    }
    // epilogue: e = exp(-sim) (|sim|<=1 -> no max needed); stash transposed; rowsum
    float rs[4][4];
#pragma unroll
    for (int i = 0; i < 4; ++i)
#pragma unroll
        for (int r = 0; r < 4; ++r) rs[i][r] = 0.f;
#pragma unroll
    for (int i = 0; i < 4; ++i) {
#pragma unroll
        for (int j = 0; j < 4; ++j) {
            ushort4_t pk;
#pragma unroll
            for (int r = 0; r < 4; ++r) {
                float e = __expf(-acc[i][j][r]);
                rs[i][r] += e;
                pk[r] = f2bf(e);
            }
            *(ushort4_t*)&smem[(wc + j * 16 + c16) * (BM + 8) + wr + i * 16 + rq] = pk;
        }
    }
#pragma unroll
    for (int d = 1; d < 16; d <<= 1)
#pragma unroll
        for (int i = 0; i < 4; ++i)
#pragma unroll
            for (int r = 0; r < 4; ++r) rs[i][r] += __shfl_xor(rs[i][r], d);
    if (c16 == 0) {
#pragma unroll
        for (int i = 0; i < 4; ++i)
#pragma unroll
            for (int r = 0; r < 4; ++r)
                atomicAdd(&S[m0 + wr + i * 16 + rq + r], rs[i][r]);
    }
    __syncthreads();
    // cooperative transposed write: ET[n0+c][m0 .. m0+BM)
    constexpr int CPR = BM / 8;  // 16-byte chunks per row
#pragma unroll
    for (int it = 0; it < (BN * CPR) / 256; ++it) {
        int flat = it * 256 + tid;
        int c = flat / CPR, ch = flat % CPR;
        *(ushort8_t*)&ET[(n0 + c) * (long)M + m0 + ch * 8] =
            *(const ushort8_t*)&smem[c * (BM + 8) + ch * 8];
    }
}

// ---------------- K3c: cat[m,k] = src[k,m] * inv_bt / S[k], transposed ----------------
__global__ __launch_bounds__(256) void k3c_scale_transpose(
        const unsigned short* __restrict__ er, const unsigned short* __restrict__ ad,
        const float* __restrict__ S, unsigned short* __restrict__ cat,
        float inv_bt, int BTr) {
    const unsigned short* src = blockIdx.y ? ad : er;
    unsigned short* dst = cat + (blockIdx.y ? (long)256 * BTr : 0);
    __shared__ __align__(16) unsigned short Tl[64][256 + 8];
    const int tid = threadIdx.x;
    const long kbase = (long)blockIdx.x * 64;
#pragma unroll
    for (int it = 0; it < 8; ++it) {
        int flat = it * 2048 + tid * 8;
        int kl = flat >> 8, m = flat & 255;
        float scale = inv_bt / S[kbase + kl];
        ushort8_t v = *(const ushort8_t*)&src[(kbase + kl) * 256 + m];
        ushort8_t o;
#pragma unroll
        for (int j = 0; j < 8; ++j) o[j] = f2bf(bf2f(v[j]) * scale);
        *(ushort8_t*)&Tl[kl][m] = o;
    }
    __syncthreads();
#pragma unroll
    for (int it = 0; it < 8; ++it) {
        int flat = it * 2048 + tid * 8;
        int m = flat >> 6, kc = flat & 63;
        ushort8_t o;
#pragma unroll
        for (int j = 0; j < 8; ++j) o[j] = Tl[kc + j][m];
        *(ushort8_t*)&dst[(long)m * BTr + kbase + kc] = o;
    }
}

// ---------------- K4: split-K GEMM: bf16 partial[sk][2048][512] = ET @ cat^T ----------------
// 8 waves as 4x2 of 64x64 tiles: 16 MFMA per 8 ds_read_b128 (2x ratio of prior version).
template<int BM, int BN, int BK>   // 256, 128, 64
__global__ __launch_bounds__(512, 4)
void k4_gemm_cat(const unsigned short* __restrict__ A, const unsigned short* __restrict__ Bc,
                 unsigned short* __restrict__ pP, long Ktot, int Kchunk) {
    __shared__ __align__(16) unsigned short As[BM * BK];
    __shared__ __align__(16) unsigned short Bs[BN * BK];
    const int tid = threadIdx.x, lane = tid & 63, wid = tid >> 6;   // wid 0..7
    const long n0 = (long)blockIdx.x * BM;        // output row (n of 2048)
    const long mc0 = (long)blockIdx.y * BN;       // concat col (of 512)
    const int sk = blockIdx.z;
    const long kbeg = (long)sk * Kchunk;
    const int wr = (wid >> 1) * 64, wc = (wid & 1) * 64;   // 4x2 waves, 64x64 tiles
    const int c16 = lane & 15, rq = (lane >> 4) * 4, swz = (lane & 7) * 8;
    f32x4 acc[4][4] = {};
    for (int kt = 0; kt < Kchunk; kt += BK) {
        stage_tile<BM, BK, 512>(A, Ktot, n0, kbeg + kt, As, tid);
        stage_tile<BN, BK, 512>(Bc, Ktot, mc0, kbeg + kt, Bs, tid);
        __syncthreads();
#pragma unroll
        for (int kk = 0; kk < BK; kk += 32) {
            const int klo = kk + (lane >> 4) * 8;
            bf16x8 af[4], bfr[4];
#pragma unroll
            for (int i = 0; i < 4; ++i) {
                af[i]  = *(const bf16x8*)&As[((wr + i * 16 + c16) * BK + klo) ^ swz];
                bfr[i] = *(const bf16x8*)&Bs[((wc + i * 16 + c16) * BK + klo) ^ swz];
            }
#pragma unroll
            for (int i = 0; i < 4; ++i)
#pragma unroll
                for (int j = 0; j < 4; ++j)
                    acc[i][j] = __builtin_amdgcn_mfma_f32_16x16x32_bf16(af[i], bfr[j], acc[i][j], 0, 0, 0);
        }
        __syncthreads();
    }
    // bf16 partials (values ~1e-5; 0.4% rel noise RMS-cancels over 16 splits -> ~1e-7 on we)
#pragma unroll
    for (int i = 0; i < 4; ++i) {
        const long row = n0 + wr + i * 16 + rq;
#pragma unroll
        for (int j = 0; j < 4; ++j) {
            const long col = mc0 + wc + j * 16 + c16;
#pragma unroll
            for (int r = 0; r < 4; ++r)
                pP[((long)sk * 2048 + row + r) * 512 + col] = f2bf(acc[i][j][r]);
        }
    }
}

// ---------------- K5: out = memory*(1 - sum we) + sum wa ----------------
__global__ __launch_bounds__(256) void k5_finalize(const float* __restrict__ mem,
                                                   const unsigned short* __restrict__ pP,
                                                   float* __restrict__ out, int splits) {
    int idx = blockIdx.x * 256 + threadIdx.x;      // 131072 threads: 2048x256 / 4
    int n = idx >> 6, m4 = (idx & 63) * 4;
    float we[4] = {0.f, 0.f, 0.f, 0.f}, wa[4] = {0.f, 0.f, 0.f, 0.f};
    for (int s = 0; s < splits; ++s) {
        const unsigned short* row = pP + ((long)s * 2048 + n) * 512;
        ushort4_t ve = *(const ushort4_t*)&row[m4];
        ushort4_t va = *(const ushort4_t*)&row[256 + m4];
#pragma unroll
        for (int j = 0; j < 4; ++j) { we[j] += bf2f(ve[j]); wa[j] += bf2f(va[j]); }
    }
    float4_t mv = ((const float4_t*)mem)[idx];
    float4_t o;
#pragma unroll
    for (int j = 0; j < 4; ++j) o[j] = mv[j] * (1.f - we[j]) + wa[j];
    ((float4_t*)out)[idx] = o;
}

extern "C" void kernel_launch(void* const* d_in, const int* in_sizes, int n_in,
                              void* d_out, int out_size, void* d_ws, size_t ws_size,
                              hipStream_t stream) {
    const float* memory = (const float*)d_in[0];
    const float* co     = (const float*)d_in[1];
    const float* Wk     = (const float*)d_in[2];
    const float* bk     = (const float*)d_in[3];
    const float* We     = (const float*)d_in[4];
    const float* be     = (const float*)d_in[5];
    const float* Wa     = (const float*)d_in[6];
    const float* ba     = (const float*)d_in[7];
    float* out = (float*)d_out;

    constexpr int BT = 16384, D = 1024, N = 2048, NC = 768;
    constexpr int SPLITK = 16;

    // Workspace (bytes), lifetime-aliased; peak exactly 145,293,312 (proven in R0):
    //  [0,64Mi)        ET (K3..K4); overlays co_bf [0,32Mi) (dead after K1)
    //  [64,72Mi) kn  [72,80Mi) er  [80,88Mi) ad   (written by K1-fused)
    //  [88,89Mi) mn  [89,90.5Mi) WcatT  [90.5Mi..) S(64Ki)
    //  [90.5625,106.5625Mi) cat  (k3c..K4)
    //  [106.5625,138.5625Mi) pP bf16 partials [16][2048][512] (K4..K5)
    char* ws = (char*)d_ws;
    unsigned short* co_bf  = (unsigned short*)(ws + 0);
    unsigned short* ET     = (unsigned short*)(ws + 0);
    unsigned short* kn     = (unsigned short*)(ws + 67108864);
    unsigned short* er     = (unsigned short*)(ws + 75497472);
    unsigned short* ad     = (unsigned short*)(ws + 83886080);
    unsigned short* mn     = (unsigned short*)(ws + 92274688);
    unsigned short* WcatT  = (unsigned short*)(ws + 93323264);
    float*          Sbuf   = (float*)(ws + 94896128);
    unsigned short* cat    = (unsigned short*)(ws + 94961664);
    unsigned short* pP     = (unsigned short*)(ws + 111738880);

    k0_cast_co<<<(BT * (long)D / 4) / 256, 256, 0, stream>>>(co, co_bf, BT * (long)D / 4);
    k0_prep_w<<<(NC * D) / 256, 256, 0, stream>>>(Wk, We, Wa, WcatT);
    k0_mn<<<N / 4, 256, 0, stream>>>(memory, mn, Sbuf, BT);

    k1_fused<128, 256, 64><<<dim3(BT / 128, 3), 512, 0, stream>>>(
        co_bf, WcatT, bk, be, ba, kn, er, ad, D);

    k3_gemm_sims<128, 128, 64><<<dim3(BT / 128, N / 128), 256, 0, stream>>>(
        kn, mn, ET, Sbuf, BT, N, 256);

    k3c_scale_transpose<<<dim3(BT / 64, 2), 256, 0, stream>>>(
        er, ad, Sbuf, cat, 1.f / (float)BT, BT);

    k4_gemm_cat<256, 128, 64><<<dim3(N / 256, 512 / 128, SPLITK), 512, 0, stream>>>(
        ET, cat, pP, (long)BT, BT / SPLITK);

    k5_finalize<<<(N * 256 / 4) / 256, 256, 0, stream>>>(memory, pP, out, SPLITK);
}

// Round 5
// 230.952 us; speedup vs baseline: 1.3114x; 1.0382x over previous
//
#include <hip/hip_runtime.h>

#define DEV __device__ __forceinline__

using f32x4    = __attribute__((ext_vector_type(4))) float;
using bf16x8   = __attribute__((ext_vector_type(8))) short;     // 8 bf16 in 4 VGPRs (guide §3)
using float4_t = __attribute__((ext_vector_type(4))) float;
using ushort4_t = __attribute__((ext_vector_type(4))) unsigned short;
using ushort8_t = __attribute__((ext_vector_type(8))) unsigned short;

DEV unsigned short f2bf(float f) {                 // RNE float->bf16 (no NaNs in this workload)
    unsigned int u = __builtin_bit_cast(unsigned int, f);
    u = (u + 0x7fffu + ((u >> 16) & 1u)) >> 16;
    return (unsigned short)u;
}
DEV float bf2f(unsigned short h) {
    unsigned int u = ((unsigned int)h) << 16;
    return __builtin_bit_cast(float, u);
}

DEV void gload_lds16(const void* g, void* l) {     // async global->LDS, width 16 (guide §5)
    __builtin_amdgcn_global_load_lds((const __attribute__((address_space(1))) void*)g,
                                     (__attribute__((address_space(3))) void*)l, 16, 0, 0);
}

// Stage a TR x 64 (bf16) tile from row-major src into LDS with T2 XOR-swizzle.
// LDS dest is linear (wave-uniform base + lane*16, HW constraint); the SOURCE chunk is
// pre-swizzled: LDS slot (row, chunk) holds global chunk (chunk ^ (row&7)) -- rule #21.
// Readers must XOR their elem offset with ((row&7)*8).
template<int TR, int TC, int NTH>
DEV void stage_tile(const unsigned short* __restrict__ src, long ld, long r0, long c0,
                    unsigned short* lds, int tid) {
    constexpr int LPR = (TC * 2) / 16;   // lanes per row (TC=64 -> 8)
    constexpr int RPI = 64 / LPR;        // rows per wave-issue (8)
    constexpr int NISSUE = TR / RPI;
    constexpr int NW = NTH / 64;
    const int wid = tid >> 6, lane = tid & 63;
    const int lr = lane / LPR;                 // row-in-group = (row & 7)
    const int lc = (lane % LPR) ^ lr;          // swizzled source chunk
#pragma unroll
    for (int ii = 0; ii < NISSUE / NW; ++ii) {
        const int i = ii * NW + wid;
        const long row = r0 + (long)i * RPI + lr;
        const unsigned short* g = src + row * ld + c0 + lc * 8;
        gload_lds16(g, lds + i * 512);   // 512 elems = 1KB per wave-issue
    }
}

// Stage a 128 x 64 A-tile DIRECTLY from fp32 src (cast in-flight), reg-staged with
// swizzled ds_write_b128 (write side swizzled <-> read side swizzled; rule #21).
// 512 threads x 2 chunks = 1024 16B-chunks. Wave global pattern: 8 rows x 256B runs.
DEV void stage_A_f32(const float* __restrict__ src, long ld, long r0, long c0,
                     unsigned short* lds, int tid) {
#pragma unroll
    for (int s = 0; s < 2; ++s) {
        const int flat = s * 512 + tid;          // 128 rows x 8 chunks
        const int row = flat >> 3, c = flat & 7;
        const float* g = src + (r0 + row) * ld + c0 + c * 8;
        float4_t v0 = *(const float4_t*)g;
        float4_t v1 = *(const float4_t*)(g + 4);
        ushort8_t o;
#pragma unroll
        for (int j = 0; j < 4; ++j) { o[j] = f2bf(v0[j]); o[4 + j] = f2bf(v1[j]); }
        const int sc = c ^ (row & 7);
        *(ushort8_t*)&lds[(row * 8 + sc) * 8] = o;
    }
}

// ---------------- K0: fused prep: WcatT bf16 transpose + mn l2norm + S zero ----------------
__global__ __launch_bounds__(256) void k0_prep(const float* __restrict__ Wk,
                                               const float* __restrict__ We,
                                               const float* __restrict__ Wa,
                                               const float* __restrict__ memory,
                                               unsigned short* __restrict__ WcatT,
                                               unsigned short* __restrict__ mn,
                                               float* __restrict__ S, int BT) {
    const int b = blockIdx.x;
    if (b < 3072) {   // WcatT[768][1024] = concat(Wk,We,Wa)^T
        long idx = (long)b * 256 + threadIdx.x;
        int j = (int)(idx >> 10), d = (int)(idx & 1023);
        const float* W = (j < 256) ? Wk : (j < 512) ? We : Wa;
        int m = j & 255;
        WcatT[idx] = f2bf(W[(long)d * 256 + m]);
    } else {          // mn = l2norm(memory) rows; zero S
        const int bb = b - 3072;
        int gid = bb * 256 + threadIdx.x;
        if (gid < BT) S[gid] = 0.f;
        int row = bb * 4 + (threadIdx.x >> 6);
        int lane = threadIdx.x & 63;
        float4_t v = ((const float4_t*)(memory + (long)row * 256))[lane];
        float ss = v[0]*v[0] + v[1]*v[1] + v[2]*v[2] + v[3]*v[3];
#pragma unroll
        for (int d = 1; d < 64; d <<= 1) ss += __shfl_xor(ss, d);
        float sc = rsqrtf(fmaxf(ss, 1e-12f));
        ushort4_t o;
#pragma unroll
        for (int j = 0; j < 4; ++j) o[j] = f2bf(v[j] * sc);
        ((ushort4_t*)(mn + (long)row * 256))[lane] = o;
    }
}

// ---------------- K1-fused: per y-tile (256 cols = one weight group) GEMM + epilogue ----
// A staged directly from fp32 controller_output (no cast kernel).
// y=0: kn = e/||e|| (softmax+l2n fused; no max-sub needed, logits ~N(0,1))
// y=1: er = sigmoid;  y=2: ad = relu.
template<int BM, int BN, int BK>   // 128, 256, 64
__global__ __launch_bounds__(512, 3)
void k1_fused(const float* __restrict__ A, const unsigned short* __restrict__ BT,
              const float* __restrict__ bk, const float* __restrict__ be,
              const float* __restrict__ ba, unsigned short* __restrict__ kn,
              unsigned short* __restrict__ er, unsigned short* __restrict__ ad, int K) {
    __shared__ __align__(16) unsigned short As[BM * BK];
    __shared__ __align__(16) unsigned short Bs[BN * BK];
    const int tid = threadIdx.x, lane = tid & 63, wid = tid >> 6;
    const long m0 = (long)blockIdx.x * BM;
    const int y = blockIdx.y;
    const int wrg = wid >> 2, wcg = wid & 3;
    const int wr = wrg * 64, wc = wcg * 64;
    const int c16 = lane & 15, rq = (lane >> 4) * 4, swz = (lane & 7) * 8;
    f32x4 acc[4][4] = {};
    for (int kt = 0; kt < K; kt += BK) {
        stage_tile<BN, BK, 512>(BT, K, (long)y * BN, kt, Bs, tid);   // async B first
        stage_A_f32(A, K, m0, kt, As, tid);                          // reg-staged fp32 A
        __syncthreads();
#pragma unroll
        for (int kk = 0; kk < BK; kk += 32) {
            const int klo = kk + (lane >> 4) * 8;
            bf16x8 af[4], bfr[4];
#pragma unroll
            for (int i = 0; i < 4; ++i) {
                af[i]  = *(const bf16x8*)&As[((wr + i * 16 + c16) * BK + klo) ^ swz];
                bfr[i] = *(const bf16x8*)&Bs[((wc + i * 16 + c16) * BK + klo) ^ swz];
            }
#pragma unroll
            for (int i = 0; i < 4; ++i)
#pragma unroll
                for (int j = 0; j < 4; ++j)
                    acc[i][j] = __builtin_amdgcn_mfma_f32_16x16x32_bf16(af[i], bfr[j], acc[i][j], 0, 0, 0);
        }
        __syncthreads();
    }
    const float* bias = (y == 0) ? bk : (y == 1) ? be : ba;
    float bj[4];
#pragma unroll
    for (int j = 0; j < 4; ++j) bj[j] = bias[wc + j * 16 + c16];

    if (y == 0) {
        // softmax + l2n: kn = e / sqrt(sum e^2), e = exp(logit) (bounded, f32-safe)
        float* redsm = (float*)As;   // [2 wrg][4 wcg][64 rows] overlay (post-loop, fenced)
#pragma unroll
        for (int i = 0; i < 4; ++i) {
            float p[4] = {0.f, 0.f, 0.f, 0.f};
#pragma unroll
            for (int j = 0; j < 4; ++j)
#pragma unroll
                for (int r = 0; r < 4; ++r) {
                    float e = __expf(acc[i][j][r] + bj[j]);
                    acc[i][j][r] = e;
                    p[r] += e * e;
                }
#pragma unroll
            for (int d = 1; d < 16; d <<= 1)
#pragma unroll
                for (int r = 0; r < 4; ++r) p[r] += __shfl_xor(p[r], d);
            if (c16 == 0) {
#pragma unroll
                for (int r = 0; r < 4; ++r)
                    redsm[(wrg * 4 + wcg) * 64 + i * 16 + rq + r] = p[r];
            }
        }
        __syncthreads();
#pragma unroll
        for (int i = 0; i < 4; ++i)
#pragma unroll
            for (int r = 0; r < 4; ++r) {
                const int row64 = i * 16 + rq + r;
                float tot = redsm[(wrg * 4 + 0) * 64 + row64] + redsm[(wrg * 4 + 1) * 64 + row64]
                          + redsm[(wrg * 4 + 2) * 64 + row64] + redsm[(wrg * 4 + 3) * 64 + row64];
                float sc = rsqrtf(tot);
                const long row = m0 + wr + row64;
#pragma unroll
                for (int j = 0; j < 4; ++j)
                    kn[row * 256 + wc + j * 16 + c16] = f2bf(acc[i][j][r] * sc);
            }
    } else {
        unsigned short* dst = (y == 1) ? er : ad;
#pragma unroll
        for (int i = 0; i < 4; ++i)
#pragma unroll
            for (int r = 0; r < 4; ++r) {
                const long row = m0 + wr + i * 16 + rq + r;
#pragma unroll
                for (int j = 0; j < 4; ++j) {
                    float v = acc[i][j][r] + bj[j];
                    float o = (y == 1) ? 1.f / (1.f + __expf(-v)) : fmaxf(v, 0.f);
                    dst[row * 256 + wc + j * 16 + c16] = f2bf(o);
                }
            }
    }
}

// ---------------- K3: E^T[n, bt] = exp(-(kn . mn)), plus rowsums S[bt] ----------------
template<int BM, int BN, int BK>
__global__ __launch_bounds__(256, 4)
void k3_gemm_sims(const unsigned short* __restrict__ A, const unsigned short* __restrict__ BT,
                  unsigned short* __restrict__ ET, float* __restrict__ S,
                  int M, int N, int K) {
    __shared__ __align__(16) unsigned short smem[BN * (BM + 8)];   // >= As(BM*BK)+Bs(BN*BK)
    unsigned short* As = smem;
    unsigned short* Bs = smem + BM * BK;
    const int tid = threadIdx.x, lane = tid & 63, wid = tid >> 6;
    const long m0 = (long)blockIdx.x * BM, n0 = (long)blockIdx.y * BN;
    const int wr = (wid >> 1) * 64, wc = (wid & 1) * 64;
    const int c16 = lane & 15, rq = (lane >> 4) * 4, swz = (lane & 7) * 8;
    f32x4 acc[4][4] = {};
    for (int kt = 0; kt < K; kt += BK) {
        stage_tile<BM, BK, 256>(A, K, m0, kt, As, tid);
        stage_tile<BN, BK, 256>(BT, K, n0, kt, Bs, tid);
        __syncthreads();
#pragma unroll
        for (int kk = 0; kk < BK; kk += 32) {
            const int klo = kk + (lane >> 4) * 8;
            bf16x8 af[4], bfr[4];
#pragma unroll
            for (int i = 0; i < 4; ++i) {
                af[i]  = *(const bf16x8*)&As[((wr + i * 16 + c16) * BK + klo) ^ swz];
                bfr[i] = *(const bf16x8*)&Bs[((wc + i * 16 + c16) * BK + klo) ^ swz];
            }
#pragma unroll
            for (int i = 0; i < 4; ++i)
#pragma unroll
                for (int j = 0; j < 4; ++j)
                    acc[i][j] = __builtin_amdgcn_mfma_f32_16x16x32_bf16(af[i], bfr[j], acc[i][j], 0, 0, 0);
        }
        __syncthreads();   // also fences last fragment reads before Tr overlays As/Bs
    }
    // epilogue: e = exp(-sim) (|sim|<=1 -> no max needed); stash transposed; rowsum
    float rs[4][4];
#pragma unroll
    for (int i = 0; i < 4; ++i)
#pragma unroll
        for (int r = 0; r < 4; ++r) rs[i][r] = 0.f;
#pragma unroll
    for (int i = 0; i < 4; ++i) {
#pragma unroll
        for (int j = 0; j < 4; ++j) {
            ushort4_t pk;
#pragma unroll
            for (int r = 0; r < 4; ++r) {
                float e = __expf(-acc[i][j][r]);
                rs[i][r] += e;
                pk[r] = f2bf(e);
            }
            *(ushort4_t*)&smem[(wc + j * 16 + c16) * (BM + 8) + wr + i * 16 + rq] = pk;
        }
    }
#pragma unroll
    for (int d = 1; d < 16; d <<= 1)
#pragma unroll
        for (int i = 0; i < 4; ++i)
#pragma unroll
            for (int r = 0; r < 4; ++r) rs[i][r] += __shfl_xor(rs[i][r], d);
    if (c16 == 0) {
#pragma unroll
        for (int i = 0; i < 4; ++i)
#pragma unroll
            for (int r = 0; r < 4; ++r)
                atomicAdd(&S[m0 + wr + i * 16 + rq + r], rs[i][r]);
    }
    __syncthreads();
    // cooperative transposed write: ET[n0+c][m0 .. m0+BM)
    constexpr int CPR = BM / 8;  // 16-byte chunks per row
#pragma unroll
    for (int it = 0; it < (BN * CPR) / 256; ++it) {
        int flat = it * 256 + tid;
        int c = flat / CPR, ch = flat % CPR;
        *(ushort8_t*)&ET[(n0 + c) * (long)M + m0 + ch * 8] =
            *(const ushort8_t*)&smem[c * (BM + 8) + ch * 8];
    }
}

// ---------------- K3c: cat[m,k] = src[k,m] * inv_bt / S[k], transposed ----------------
__global__ __launch_bounds__(256) void k3c_scale_transpose(
        const unsigned short* __restrict__ er, const unsigned short* __restrict__ ad,
        const float* __restrict__ S, unsigned short* __restrict__ cat,
        float inv_bt, int BTr) {
    const unsigned short* src = blockIdx.y ? ad : er;
    unsigned short* dst = cat + (blockIdx.y ? (long)256 * BTr : 0);
    __shared__ __align__(16) unsigned short Tl[64][256 + 8];
    const int tid = threadIdx.x;
    const long kbase = (long)blockIdx.x * 64;
#pragma unroll
    for (int it = 0; it < 8; ++it) {
        int flat = it * 2048 + tid * 8;
        int kl = flat >> 8, m = flat & 255;
        float scale = inv_bt / S[kbase + kl];
        ushort8_t v = *(const ushort8_t*)&src[(kbase + kl) * 256 + m];
        ushort8_t o;
#pragma unroll
        for (int j = 0; j < 8; ++j) o[j] = f2bf(bf2f(v[j]) * scale);
        *(ushort8_t*)&Tl[kl][m] = o;
    }
    __syncthreads();
#pragma unroll
    for (int it = 0; it < 8; ++it) {
        int flat = it * 2048 + tid * 8;
        int m = flat >> 6, kc = flat & 63;
        ushort8_t o;
#pragma unroll
        for (int j = 0; j < 8; ++j) o[j] = Tl[kc + j][m];
        *(ushort8_t*)&dst[(long)m * BTr + kbase + kc] = o;
    }
}

// ---------------- K4: split-K GEMM: bf16 partial[sk][2048][512] = ET @ cat^T ----------------
// 8 waves as 4x2 of 64x64 tiles: 16 MFMA per 8 ds_read_b128.
template<int BM, int BN, int BK>   // 256, 128, 64
__global__ __launch_bounds__(512, 4)
void k4_gemm_cat(const unsigned short* __restrict__ A, const unsigned short* __restrict__ Bc,
                 unsigned short* __restrict__ pP, long Ktot, int Kchunk) {
    __shared__ __align__(16) unsigned short As[BM * BK];
    __shared__ __align__(16) unsigned short Bs[BN * BK];
    const int tid = threadIdx.x, lane = tid & 63, wid = tid >> 6;   // wid 0..7
    const long n0 = (long)blockIdx.x * BM;        // output row (n of 2048)
    const long mc0 = (long)blockIdx.y * BN;       // concat col (of 512)
    const int sk = blockIdx.z;
    const long kbeg = (long)sk * Kchunk;
    const int wr = (wid >> 1) * 64, wc = (wid & 1) * 64;   // 4x2 waves, 64x64 tiles
    const int c16 = lane & 15, rq = (lane >> 4) * 4, swz = (lane & 7) * 8;
    f32x4 acc[4][4] = {};
    for (int kt = 0; kt < Kchunk; kt += BK) {
        stage_tile<BM, BK, 512>(A, Ktot, n0, kbeg + kt, As, tid);
        stage_tile<BN, BK, 512>(Bc, Ktot, mc0, kbeg + kt, Bs, tid);
        __syncthreads();
#pragma unroll
        for (int kk = 0; kk < BK; kk += 32) {
            const int klo = kk + (lane >> 4) * 8;
            bf16x8 af[4], bfr[4];
#pragma unroll
            for (int i = 0; i < 4; ++i) {
                af[i]  = *(const bf16x8*)&As[((wr + i * 16 + c16) * BK + klo) ^ swz];
                bfr[i] = *(const bf16x8*)&Bs[((wc + i * 16 + c16) * BK + klo) ^ swz];
            }
#pragma unroll
            for (int i = 0; i < 4; ++i)
#pragma unroll
                for (int j = 0; j < 4; ++j)
                    acc[i][j] = __builtin_amdgcn_mfma_f32_16x16x32_bf16(af[i], bfr[j], acc[i][j], 0, 0, 0);
        }
        __syncthreads();
    }
    // bf16 partials (values ~1e-5; 0.4% rel noise RMS-cancels over 16 splits -> ~1e-7 on we)
#pragma unroll
    for (int i = 0; i < 4; ++i) {
        const long row = n0 + wr + i * 16 + rq;
#pragma unroll
        for (int j = 0; j < 4; ++j) {
            const long col = mc0 + wc + j * 16 + c16;
#pragma unroll
            for (int r = 0; r < 4; ++r)
                pP[((long)sk * 2048 + row + r) * 512 + col] = f2bf(acc[i][j][r]);
        }
    }
}

// ---------------- K5: out = memory*(1 - sum we) + sum wa ----------------
__global__ __launch_bounds__(256) void k5_finalize(const float* __restrict__ mem,
                                                   const unsigned short* __restrict__ pP,
                                                   float* __restrict__ out, int splits) {
    int idx = blockIdx.x * 256 + threadIdx.x;      // 131072 threads: 2048x256 / 4
    int n = idx >> 6, m4 = (idx & 63) * 4;
    float we[4] = {0.f, 0.f, 0.f, 0.f}, wa[4] = {0.f, 0.f, 0.f, 0.f};
    for (int s = 0; s < splits; ++s) {
        const unsigned short* row = pP + ((long)s * 2048 + n) * 512;
        ushort4_t ve = *(const ushort4_t*)&row[m4];
        ushort4_t va = *(const ushort4_t*)&row[256 + m4];
#pragma unroll
        for (int j = 0; j < 4; ++j) { we[j] += bf2f(ve[j]); wa[j] += bf2f(va[j]); }
    }
    float4_t mv = ((const float4_t*)mem)[idx];
    float4_t o;
#pragma unroll
    for (int j = 0; j < 4; ++j) o[j] = mv[j] * (1.f - we[j]) + wa[j];
    ((float4_t*)out)[idx] = o;
}

extern "C" void kernel_launch(void* const* d_in, const int* in_sizes, int n_in,
                              void* d_out, int out_size, void* d_ws, size_t ws_size,
                              hipStream_t stream) {
    const float* memory = (const float*)d_in[0];
    const float* co     = (const float*)d_in[1];
    const float* Wk     = (const float*)d_in[2];
    const float* bk     = (const float*)d_in[3];
    const float* We     = (const float*)d_in[4];
    const float* be     = (const float*)d_in[5];
    const float* Wa     = (const float*)d_in[6];
    const float* ba     = (const float*)d_in[7];
    float* out = (float*)d_out;

    constexpr int BT = 16384, D = 1024, N = 2048;
    constexpr int SPLITK = 16;

    // Workspace (bytes), lifetime-aliased; peak ~138.6 MiB (d_ws is 256 MiB per fill counters):
    //  [0,64Mi)   ET (K3..K4)
    //  [64,72Mi) kn  [72,80Mi) er  [80,88Mi) ad   (written by K1-fused)
    //  [88,89Mi) mn  [89,90.5Mi) WcatT  [90.5Mi..) S(64Ki)
    //  [90.5625,106.5625Mi) cat  (k3c..K4)
    //  [106.5625,138.5625Mi) pP bf16 partials [16][2048][512] (K4..K5)
    char* ws = (char*)d_ws;
    unsigned short* ET     = (unsigned short*)(ws + 0);
    unsigned short* kn     = (unsigned short*)(ws + 67108864);
    unsigned short* er     = (unsigned short*)(ws + 75497472);
    unsigned short* ad     = (unsigned short*)(ws + 83886080);
    unsigned short* mn     = (unsigned short*)(ws + 92274688);
    unsigned short* WcatT  = (unsigned short*)(ws + 93323264);
    float*          Sbuf   = (float*)(ws + 94896128);
    unsigned short* cat    = (unsigned short*)(ws + 94961664);
    unsigned short* pP     = (unsigned short*)(ws + 111738880);

    k0_prep<<<3072 + N / 4, 256, 0, stream>>>(Wk, We, Wa, memory, WcatT, mn, Sbuf, BT);

    k1_fused<128, 256, 64><<<dim3(BT / 128, 3), 512, 0, stream>>>(
        co, WcatT, bk, be, ba, kn, er, ad, D);

    k3_gemm_sims<128, 128, 64><<<dim3(BT / 128, N / 128), 256, 0, stream>>>(
        kn, mn, ET, Sbuf, BT, N, 256);

    k3c_scale_transpose<<<dim3(BT / 64, 2), 256, 0, stream>>>(
        er, ad, Sbuf, cat, 1.f / (float)BT, BT);

    k4_gemm_cat<256, 128, 64><<<dim3(N / 256, 512 / 128, SPLITK), 512, 0, stream>>>(
        ET, cat, pP, (long)BT, BT / SPLITK);

    k5_finalize<<<(N * 256 / 4) / 256, 256, 0, stream>>>(memory, pP, out, SPLITK);
}